// Round 4
// baseline (241.979 us; speedup 1.0000x reference)
//
#include <hip/hip_runtime.h>
#include <math.h>

#define N_PTS 50000
#define CCH   64
#define KP    15
#define NH    32
#define SIGMA 0.7f
#define BN_EPS 1e-5f
#define LEAKY 0.1f
#define QB    16
#define CWS   18           // cwT row stride in bf16 (16 q + 2 pad -> 2-way banks, free)
#define STATS_BLOCKS 1024

typedef short bf16x8 __attribute__((ext_vector_type(8)));
typedef float floatx4 __attribute__((ext_vector_type(4)));

__device__ __forceinline__ unsigned short f2b(float f) {
    union { float f; unsigned u; } v; v.f = f;
    return (unsigned short)((v.u + 0x7FFFu + ((v.u >> 16) & 1u)) >> 16);  // RNE
}
__device__ __forceinline__ float b2f(unsigned short b) {
    union { unsigned u; float f; } v; v.u = ((unsigned)b) << 16;
    return v.f;
}

// ---------- K1: blocks [0,STATS): h = sf@W1 -> hst (bf16) + BN sum/sumsq.
//             blocks [STATS, STATS+30): repack W2 into bf16 B-fragment order. ----------
__global__ __launch_bounds__(256) void k_prep(const float* __restrict__ sf,
                                              const float* __restrict__ W1,
                                              const float* __restrict__ W2,
                                              float* __restrict__ bn,
                                              unsigned short* __restrict__ hst,
                                              unsigned short* __restrict__ w2b) {
    int t = threadIdx.x;
    if (blockIdx.x >= STATS_BLOCKS) {
        // w2b[((tile*2+kstep)*64+lane)*8+j] = bf16(W2[k][n]),
        //   k = kstep*32 + (lane>>4)*8 + j, n = tile*16 + (lane&15)
        int g = (blockIdx.x - STATS_BLOCKS) * 256 + t;   // 7680 exactly
        int lane = g & 63, s = (g >> 6) & 1, tt = g >> 7;
        int col = lane & 15, quad = lane >> 4;
        int base = (s * 32 + quad * 8) * 960 + tt * 16 + col;
        ushort4 lo, hi;
        lo.x = f2b(W2[base + 0 * 960]); lo.y = f2b(W2[base + 1 * 960]);
        lo.z = f2b(W2[base + 2 * 960]); lo.w = f2b(W2[base + 3 * 960]);
        hi.x = f2b(W2[base + 4 * 960]); hi.y = f2b(W2[base + 5 * 960]);
        hi.z = f2b(W2[base + 6 * 960]); hi.w = f2b(W2[base + 7 * 960]);
        *(ushort4*)(w2b + g * 8)     = lo;
        *(ushort4*)(w2b + g * 8 + 4) = hi;
        return;
    }
    int c = t & 63, ml = t >> 6;
    float w1c[64];
    #pragma unroll
    for (int i = 0; i < 64; ++i) w1c[i] = W1[i * 64 + c];
    __shared__ float rows[4][64];
    float acc_s = 0.f, acc_q = 0.f;
    for (int m0 = blockIdx.x * 4; m0 < N_PTS; m0 += STATS_BLOCKS * 4) {
        __syncthreads();
        ((float*)rows)[t] = sf[m0 * 64 + t];
        __syncthreads();
        float h = 0.f;
        #pragma unroll
        for (int i4 = 0; i4 < 16; ++i4) {
            float4 r = *(const float4*)&rows[ml][i4 * 4];
            h += r.x * w1c[i4 * 4] + r.y * w1c[i4 * 4 + 1]
               + r.z * w1c[i4 * 4 + 2] + r.w * w1c[i4 * 4 + 3];
        }
        acc_s += h;
        acc_q += h * h;
        hst[(m0 + ml) * 64 + c] = f2b(h);      // 128B/wave coalesced
    }
    __shared__ float red[2][256];
    red[0][t] = acc_s; red[1][t] = acc_q;
    __syncthreads();
    if (t < 64) {
        float s = red[0][t] + red[0][64 + t] + red[0][128 + t] + red[0][192 + t];
        float q = red[1][t] + red[1][64 + t] + red[1][128 + t] + red[1][192 + t];
        atomicAdd(&bn[t], s);
        atomicAdd(&bn[64 + t], q);
    }
}

// ---------- K2: fused main kernel, 1024 threads (16 waves), 1 wave per query in phase B ----------
__global__ __launch_bounds__(1024, 8) void k_main(
    const float* __restrict__ q_pts, const float* __restrict__ s_pts,
    const float* __restrict__ s_feats, const int* __restrict__ nb,
    const float* __restrict__ kpts, const float* __restrict__ gamma,
    const float* __restrict__ beta, const float* __restrict__ bn,
    const float* __restrict__ b2, const unsigned short* __restrict__ w2b,
    const unsigned short* __restrict__ hst, float* __restrict__ out) {

    __shared__ __align__(16) unsigned short cwT[960 * CWS];  // 34.56 KB: cw[n][q] bf16
    __shared__ float abS[128];                               // BN fold a[64], b[64]
    __shared__ float kp[48];
    __shared__ int   nCnt[QB];
    __shared__ int   nPack[QB][NH];                          // idx | (k<<20)
    __shared__ float nInf[QB][NH];

    int t = threadIdx.x;
    int lane = t & 63, wv = t >> 6;       // wv in [0,16)
    int m0 = blockIdx.x * QB;

    if (t < 64) {   // inline BN finalize
        float mu  = bn[t] * (1.0f / N_PTS);
        float var = bn[64 + t] * (1.0f / N_PTS) - mu * mu;
        float a   = gamma[t] * rsqrtf(var + BN_EPS);
        abS[t]      = a;
        abS[64 + t] = beta[t] - mu * a;
    } else if (t < 64 + 45) {
        kp[t - 64] = kpts[t - 64];
    } else if (t >= 128 && t < 128 + QB) {
        nCnt[t - 128] = 0;
    }
    __syncthreads();

    // ---- A-fragment build (all waves; needed by phase A): fold BN + leaky on bf16 h ----
    int row = lane & 15, half = lane >> 4;
    bf16x8 a0, a1;
    {
        const unsigned short* hrow = hst + (m0 + row) * 64 + half * 8;
        bf16x8 r0 = *(const bf16x8*)(hrow);        // c = half*8 + j
        bf16x8 r1 = *(const bf16x8*)(hrow + 32);   // c = 32 + half*8 + j
        #pragma unroll
        for (int j = 0; j < 8; ++j) {
            int c0 = half * 8 + j;
            float g0 = abS[c0] * b2f((unsigned short)r0[j]) + abS[64 + c0];
            g0 = g0 > 0.f ? g0 : LEAKY * g0;
            a0[j] = (short)f2b(g0);
            int c1 = 32 + c0;
            float g1 = abS[c1] * b2f((unsigned short)r1[j]) + abS[64 + c1];
            g1 = g1 > 0.f ? g1 : LEAKY * g1;
            a1[j] = (short)f2b(g1);
        }
    }

    // ---- phase 1: neighbor 1-NN kernel point + influence (one task per thread) ----
    if (t < QB * NH) {
        int q = t >> 5, hh = t & 31;
        int m = m0 + q;
        int idx = nb[m * NH + hh];
        float px = s_pts[idx * 3 + 0] - q_pts[m * 3 + 0];
        float py = s_pts[idx * 3 + 1] - q_pts[m * 3 + 1];
        float pz = s_pts[idx * 3 + 2] - q_pts[m * 3 + 2];
        float best = 1e30f; int bi = 0;
        #pragma unroll
        for (int k = 0; k < KP; ++k) {
            float dx = px - kp[k * 3], dy = py - kp[k * 3 + 1], dz = pz - kp[k * 3 + 2];
            float d = dx * dx + dy * dy + dz * dz;
            if (d < best) { best = d; bi = k; }
        }
        float infl = 1.f - sqrtf(best) * (1.0f / SIGMA);
        if (infl > 0.f) {
            int pos = atomicAdd(&nCnt[q], 1);
            nPack[q][pos] = idx | (bi << 20);
            nInf[q][pos]  = infl;
        }
    }

    // ---- phase A: cw = G @ W2 via MFMA; 60 n-tiles over 16 waves ----
    {
        int col = lane & 15, quad = lane >> 4;
        for (int tt = wv; tt < 60; tt += 16) {
            bf16x8 bf0 = *(const bf16x8*)(w2b + ((tt * 2 + 0) * 64 + lane) * 8);
            bf16x8 bf1 = *(const bf16x8*)(w2b + ((tt * 2 + 1) * 64 + lane) * 8);
            floatx4 acc = {0.f, 0.f, 0.f, 0.f};
            acc = __builtin_amdgcn_mfma_f32_16x16x32_bf16(a0, bf0, acc, 0, 0, 0);
            acc = __builtin_amdgcn_mfma_f32_16x16x32_bf16(a1, bf1, acc, 0, 0, 0);
            int n = tt * 16 + col;
            float bb = b2[n];
            unsigned short* dst = &cwT[n * CWS + quad * 4];   // D: row(q)=quad*4+reg
            ushort2 w01, w23;
            w01.x = f2b(acc[0] + bb); w01.y = f2b(acc[1] + bb);
            w23.x = f2b(acc[2] + bb); w23.y = f2b(acc[3] + bb);
            *(ushort2*)(dst)     = w01;
            *(ushort2*)(dst + 2) = w23;
        }
    }
    __syncthreads();

    // ---- phase B: wave wv owns query q=wv; fully-pipelined independent gathers ----
    {
        int q = wv;
        int c = lane;
        int na = nCnt[q];
        float acc = 0.f;
        int jj = 0;
        for (; jj + 4 <= na; jj += 4) {
            int   p0 = nPack[q][jj + 0], p1 = nPack[q][jj + 1];
            int   p2 = nPack[q][jj + 2], p3 = nPack[q][jj + 3];
            float i0 = nInf[q][jj + 0], i1 = nInf[q][jj + 1];
            float i2 = nInf[q][jj + 2], i3 = nInf[q][jj + 3];
            float f0 = s_feats[(p0 & 0xFFFFF) * 64 + c];
            float f1 = s_feats[(p1 & 0xFFFFF) * 64 + c];
            float f2 = s_feats[(p2 & 0xFFFFF) * 64 + c];
            float f3 = s_feats[(p3 & 0xFFFFF) * 64 + c];
            float w0 = b2f(cwT[((p0 >> 20) * 64 + c) * CWS + q]);
            float w1 = b2f(cwT[((p1 >> 20) * 64 + c) * CWS + q]);
            float w2 = b2f(cwT[((p2 >> 20) * 64 + c) * CWS + q]);
            float w3 = b2f(cwT[((p3 >> 20) * 64 + c) * CWS + q]);
            acc += i0 * f0 * w0;
            acc += i1 * f1 * w1;
            acc += i2 * f2 * w2;
            acc += i3 * f3 * w3;
        }
        for (; jj < na; ++jj) {
            int p0 = nPack[q][jj];
            float f0 = s_feats[(p0 & 0xFFFFF) * 64 + c];
            float w0 = b2f(cwT[((p0 >> 20) * 64 + c) * CWS + q]);
            acc += nInf[q][jj] * f0 * w0;
        }
        out[(m0 + q) * 64 + c] = acc;
    }
}

extern "C" void kernel_launch(void* const* d_in, const int* in_sizes, int n_in,
                              void* d_out, int out_size, void* d_ws, size_t ws_size,
                              hipStream_t stream) {
    const float* q_pts   = (const float*)d_in[0];
    const float* s_pts   = (const float*)d_in[1];
    const float* s_feats = (const float*)d_in[2];
    const int*   nb      = (const int*)d_in[3];
    const float* kpts    = (const float*)d_in[4];
    const float* W1      = (const float*)d_in[5];
    const float* gamma   = (const float*)d_in[6];
    const float* beta    = (const float*)d_in[7];
    const float* W2      = (const float*)d_in[8];
    const float* b2      = (const float*)d_in[9];
    float* out = (float*)d_out;

    float* ws = (float*)d_ws;
    float* bn = ws;                                        // 128 fp32
    unsigned short* w2b = (unsigned short*)(ws + 128);     // 61440 bf16 (122880 B)
    unsigned short* hst = w2b + 61440;                     // 50000*64 bf16 (6.4 MB)

    hipMemsetAsync(bn, 0, 128 * sizeof(float), stream);
    k_prep<<<STATS_BLOCKS + 30, 256, 0, stream>>>(s_feats, W1, W2, bn, hst, w2b);
    k_main<<<N_PTS / QB, 1024, 0, stream>>>(q_pts, s_pts, s_feats, nb, kpts,
                                            gamma, beta, bn, b2, w2b, hst, out);
}

// Round 5
// 185.960 us; speedup vs baseline: 1.3012x; 1.3012x over previous
//
#include <hip/hip_runtime.h>
#include <math.h>

#define N_PTS 50000
#define CCH   64
#define KP    15
#define NH    32
#define SIGMA 0.7f
#define BN_EPS 1e-5f
#define LEAKY 0.1f
#define QB    16
#define CWS   17           // cwT row stride in bf16: 34B lane stride -> 2-way banks (free)
#define STATS_BLOCKS 1024

typedef short bf16x8 __attribute__((ext_vector_type(8)));
typedef float floatx4 __attribute__((ext_vector_type(4)));

__device__ __forceinline__ unsigned short f2b(float f) {
    union { float f; unsigned u; } v; v.f = f;
    return (unsigned short)((v.u + 0x7FFFu + ((v.u >> 16) & 1u)) >> 16);  // RNE
}
__device__ __forceinline__ float b2f(unsigned short b) {
    union { unsigned u; float f; } v; v.u = ((unsigned)b) << 16;
    return v.f;
}

// ---------- K1: blocks [0,STATS): h = sf@W1 -> hst (bf16) + BN sum/sumsq.
//             blocks [STATS, STATS+30): repack W2 into bf16 B-fragment order. ----------
__global__ __launch_bounds__(256) void k_prep(const float* __restrict__ sf,
                                              const float* __restrict__ W1,
                                              const float* __restrict__ W2,
                                              float* __restrict__ bn,
                                              unsigned short* __restrict__ hst,
                                              unsigned short* __restrict__ w2b) {
    int t = threadIdx.x;
    if (blockIdx.x >= STATS_BLOCKS) {
        // w2b[((tile*2+kstep)*64+lane)*8+j] = bf16(W2[k][n]),
        //   k = kstep*32 + (lane>>4)*8 + j, n = tile*16 + (lane&15)
        int g = (blockIdx.x - STATS_BLOCKS) * 256 + t;   // 7680 exactly
        int lane = g & 63, s = (g >> 6) & 1, tt = g >> 7;
        int col = lane & 15, quad = lane >> 4;
        int base = (s * 32 + quad * 8) * 960 + tt * 16 + col;
        ushort4 lo, hi;
        lo.x = f2b(W2[base + 0 * 960]); lo.y = f2b(W2[base + 1 * 960]);
        lo.z = f2b(W2[base + 2 * 960]); lo.w = f2b(W2[base + 3 * 960]);
        hi.x = f2b(W2[base + 4 * 960]); hi.y = f2b(W2[base + 5 * 960]);
        hi.z = f2b(W2[base + 6 * 960]); hi.w = f2b(W2[base + 7 * 960]);
        *(ushort4*)(w2b + g * 8)     = lo;
        *(ushort4*)(w2b + g * 8 + 4) = hi;
        return;
    }
    int c = t & 63, ml = t >> 6;
    float w1c[64];
    #pragma unroll
    for (int i = 0; i < 64; ++i) w1c[i] = W1[i * 64 + c];
    __shared__ float rows[4][64];
    float acc_s = 0.f, acc_q = 0.f;
    for (int m0 = blockIdx.x * 4; m0 < N_PTS; m0 += STATS_BLOCKS * 4) {
        __syncthreads();
        ((float*)rows)[t] = sf[m0 * 64 + t];
        __syncthreads();
        float h = 0.f;
        #pragma unroll
        for (int i4 = 0; i4 < 16; ++i4) {
            float4 r = *(const float4*)&rows[ml][i4 * 4];
            h += r.x * w1c[i4 * 4] + r.y * w1c[i4 * 4 + 1]
               + r.z * w1c[i4 * 4 + 2] + r.w * w1c[i4 * 4 + 3];
        }
        acc_s += h;
        acc_q += h * h;
        hst[(m0 + ml) * 64 + c] = f2b(h);      // 128B/wave coalesced
    }
    __shared__ float red[2][256];
    red[0][t] = acc_s; red[1][t] = acc_q;
    __syncthreads();
    if (t < 64) {
        float s = red[0][t] + red[0][64 + t] + red[0][128 + t] + red[0][192 + t];
        float q = red[1][t] + red[1][64 + t] + red[1][128 + t] + red[1][192 + t];
        atomicAdd(&bn[t], s);
        atomicAdd(&bn[64 + t], q);
    }
}

// ---------- K2: fused main kernel. 512 threads (8 waves), QB=16 queries/block. ----------
// launch_bounds min-waves=4 -> VGPR cap 128 (NOT 8: round-4 showed that forces
// a 64-reg unified budget -> spills -> 231MB scratch traffic). Actual ~60 VGPRs
// lets HW reach 4 blocks/CU (32 waves) via LDS fit alone.
__global__ __launch_bounds__(512, 4) void k_main(
    const float* __restrict__ q_pts, const float* __restrict__ s_pts,
    const float* __restrict__ s_feats, const int* __restrict__ nb,
    const float* __restrict__ kpts, const float* __restrict__ gamma,
    const float* __restrict__ beta, const float* __restrict__ bn,
    const float* __restrict__ b2, const unsigned short* __restrict__ w2b,
    const unsigned short* __restrict__ hst, float* __restrict__ out) {

    __shared__ __align__(16) unsigned short cwT[960 * CWS];  // 32.64 KB: cw[n][q] bf16
    __shared__ float abS[128];                               // BN fold a[64], b[64]
    __shared__ float kp[48];
    __shared__ int      nCnt[QB];
    __shared__ unsigned nPack[QB][NH];    // idx(0:15) | k(16:19) | infl_q12(20:31)

    int t = threadIdx.x;
    int lane = t & 63, wv = t >> 6;       // wv in [0,8)
    int m0 = blockIdx.x * QB;

    // ---- init LDS ----
    if (t < 64) {   // inline BN finalize
        float mu  = bn[t] * (1.0f / N_PTS);
        float var = bn[64 + t] * (1.0f / N_PTS) - mu * mu;
        float a   = gamma[t] * rsqrtf(var + BN_EPS);
        abS[t]      = a;
        abS[64 + t] = beta[t] - mu * a;
    } else if (t >= 64 && t < 64 + 45) {
        kp[t - 64] = kpts[t - 64];
    } else if (t >= 128 && t < 128 + QB) {
        nCnt[t - 128] = 0;
    }
    ((unsigned*)nPack)[t] = 0u;           // zero-pad for branch-free phase B
    __syncthreads();

    // ---- issue phase-1 & A-frag loads early ----
    int q1 = t >> 5, hh = t & 31;         // exactly 512 tasks
    int m1 = m0 + q1;
    int idx = nb[m1 * NH + hh];           // coalesced
    float qx = q_pts[m1 * 3 + 0], qy = q_pts[m1 * 3 + 1], qz = q_pts[m1 * 3 + 2];

    int row = lane & 15, half = lane >> 4;
    const unsigned short* hrow = hst + (m0 + row) * 64 + half * 8;
    bf16x8 r0 = *(const bf16x8*)(hrow);        // c = half*8 + j
    bf16x8 r1 = *(const bf16x8*)(hrow + 32);   // c = 32 + half*8 + j

    // ---- A-fragment build: fold BN + leaky on bf16 h (overlaps nb latency) ----
    bf16x8 a0, a1;
    #pragma unroll
    for (int j = 0; j < 8; ++j) {
        int c0 = half * 8 + j;
        float g0 = abS[c0] * b2f((unsigned short)r0[j]) + abS[64 + c0];
        g0 = g0 > 0.f ? g0 : LEAKY * g0;
        a0[j] = (short)f2b(g0);
        int c1 = 32 + c0;
        float g1 = abS[c1] * b2f((unsigned short)r1[j]) + abS[64 + c1];
        g1 = g1 > 0.f ? g1 : LEAKY * g1;
        a1[j] = (short)f2b(g1);
    }

    // ---- issue s_pts gather (idx has landed during frag build) ----
    float sx = s_pts[idx * 3 + 0];
    float sy = s_pts[idx * 3 + 1];
    float sz = s_pts[idx * 3 + 2];

    // ---- phase A: cw = G @ W2 via MFMA; 60 n-tiles over 8 waves (overlaps s_pts) ----
    {
        int col = lane & 15, quad = lane >> 4;
        for (int tt = wv; tt < 60; tt += 8) {
            bf16x8 bf0 = *(const bf16x8*)(w2b + ((tt * 2 + 0) * 64 + lane) * 8);
            bf16x8 bf1 = *(const bf16x8*)(w2b + ((tt * 2 + 1) * 64 + lane) * 8);
            floatx4 acc = {0.f, 0.f, 0.f, 0.f};
            acc = __builtin_amdgcn_mfma_f32_16x16x32_bf16(a0, bf0, acc, 0, 0, 0);
            acc = __builtin_amdgcn_mfma_f32_16x16x32_bf16(a1, bf1, acc, 0, 0, 0);
            int n = tt * 16 + col;
            float bb = b2[n];
            unsigned short* dst = &cwT[n * CWS + quad * 4];   // D: row(q)=quad*4+reg
            ushort2 w01, w23;
            w01.x = f2b(acc[0] + bb); w01.y = f2b(acc[1] + bb);
            w23.x = f2b(acc[2] + bb); w23.y = f2b(acc[3] + bb);
            *(ushort2*)(dst)     = w01;
            *(ushort2*)(dst + 2) = w23;
        }
    }

    // ---- finish phase 1: 1-NN kernel point + influence, packed compacted append ----
    {
        float px = sx - qx, py = sy - qy, pz = sz - qz;
        float best = 1e30f; int bi = 0;
        #pragma unroll
        for (int k = 0; k < KP; ++k) {
            float dx = px - kp[k * 3], dy = py - kp[k * 3 + 1], dz = pz - kp[k * 3 + 2];
            float d = dx * dx + dy * dy + dz * dz;
            if (d < best) { best = d; bi = k; }
        }
        float infl = 1.f - sqrtf(best) * (1.0f / SIGMA);
        if (infl > 0.f) {
            int iq = (int)(infl * 4095.f + 0.5f);
            int pos = atomicAdd(&nCnt[q1], 1);
            nPack[q1][pos] = (unsigned)idx | ((unsigned)bi << 16) | ((unsigned)iq << 20);
        }
    }
    __syncthreads();

    // ---- phase B: wave wv owns queries qa=2wv, qb=2wv+1; 4 gathers in flight ----
    {
        int qa = wv * 2, qb = wv * 2 + 1;
        int c = lane;
        int naA = nCnt[qa], naB = nCnt[qb];
        int na = naA > naB ? naA : naB;
        float accA = 0.f, accB = 0.f;
        for (int jj = 0; jj < na; jj += 2) {
            uint2 pa = *(const uint2*)&nPack[qa][jj];   // zero-padded: safe past count
            uint2 pb = *(const uint2*)&nPack[qb][jj];
            float fA0 = s_feats[(pa.x & 0xFFFFu) * 64 + c];
            float fA1 = s_feats[(pa.y & 0xFFFFu) * 64 + c];
            float fB0 = s_feats[(pb.x & 0xFFFFu) * 64 + c];
            float fB1 = s_feats[(pb.y & 0xFFFFu) * 64 + c];
            float wA0 = b2f(cwT[(((pa.x >> 16) & 15u) * 64 + c) * CWS + qa]);
            float wA1 = b2f(cwT[(((pa.y >> 16) & 15u) * 64 + c) * CWS + qa]);
            float wB0 = b2f(cwT[(((pb.x >> 16) & 15u) * 64 + c) * CWS + qb]);
            float wB1 = b2f(cwT[(((pb.y >> 16) & 15u) * 64 + c) * CWS + qb]);
            float iA0 = (float)(pa.x >> 20) * (1.f / 4095.f);
            float iA1 = (float)(pa.y >> 20) * (1.f / 4095.f);
            float iB0 = (float)(pb.x >> 20) * (1.f / 4095.f);
            float iB1 = (float)(pb.y >> 20) * (1.f / 4095.f);
            accA += iA0 * fA0 * wA0 + iA1 * fA1 * wA1;
            accB += iB0 * fB0 * wB0 + iB1 * fB1 * wB1;
        }
        out[(m0 + qa) * 64 + c] = accA;
        out[(m0 + qb) * 64 + c] = accB;
    }
}

extern "C" void kernel_launch(void* const* d_in, const int* in_sizes, int n_in,
                              void* d_out, int out_size, void* d_ws, size_t ws_size,
                              hipStream_t stream) {
    const float* q_pts   = (const float*)d_in[0];
    const float* s_pts   = (const float*)d_in[1];
    const float* s_feats = (const float*)d_in[2];
    const int*   nb      = (const int*)d_in[3];
    const float* kpts    = (const float*)d_in[4];
    const float* W1      = (const float*)d_in[5];
    const float* gamma   = (const float*)d_in[6];
    const float* beta    = (const float*)d_in[7];
    const float* W2      = (const float*)d_in[8];
    const float* b2      = (const float*)d_in[9];
    float* out = (float*)d_out;

    float* ws = (float*)d_ws;
    float* bn = ws;                                        // 128 fp32
    unsigned short* w2b = (unsigned short*)(ws + 128);     // 61440 bf16 (122880 B)
    unsigned short* hst = w2b + 61440;                     // 50000*64 bf16 (6.4 MB)

    hipMemsetAsync(bn, 0, 128 * sizeof(float), stream);
    k_prep<<<STATS_BLOCKS + 30, 256, 0, stream>>>(s_feats, W1, W2, bn, hst, w2b);
    k_main<<<N_PTS / QB, 512, 0, stream>>>(q_pts, s_pts, s_feats, nb, kpts,
                                           gamma, beta, bn, b2, w2b, hst, out);
}